// Round 6
// baseline (314.026 us; speedup 1.0000x reference)
//
#include <hip/hip_runtime.h>

typedef unsigned short u16;
typedef __bf16 bf16x8 __attribute__((ext_vector_type(8)));
typedef float f32x16 __attribute__((ext_vector_type(16)));

// fp32 -> bf16 round-to-nearest-even (finite values; no NaN path needed here)
__device__ __forceinline__ u16 f2bf(float f) {
  unsigned int u = __float_as_uint(f);
  return (u16)((u + 0x7fffu + ((u >> 16) & 1u)) >> 16);
}

// ---------------------------------------------------------------------------
// out = bf16(x) @ Wtil^T + bias, ONE uniform GEMM 2048 x 7168 x 4096, where
// Wtil folds the mean-over-perms: Wtil_i[d,g*512+f] = sum_j C_i[g,j]*W_i[d,j*512+f].
// Round 6 = round 5 with the prologue race FIXED: vmcnt(0) + s_barrier BEFORE
// the first fragment reads (vmcnt only covers own-wave loads; the barrier is
// what publishes other waves' staged rows). Everything else identical:
// 32x32x16 MFMA, read-ahead (phase p reads feed phase p+1 MFMA), one barrier
// per phase, FIFO-derived counted vmcnt guards.
// ---------------------------------------------------------------------------

// ---------------------------------------------------------------------------
// Kernel 1: prep (one dispatch).  [unchanged — near roofline]
// ---------------------------------------------------------------------------
__global__ __launch_bounds__(256) void k_prep(
    const float* __restrict__ x,
    const int* p0, const int* p1, const int* p2, const int* p3,
    const int* p4, const int* p5, const int* p6,
    const float* W0, const float* W1, const float* W2, const float* W3,
    const float* W4, const float* W5, const float* W6,
    u16* __restrict__ Xb16, u16* __restrict__ Wtil) {
  __shared__ float sC[64];                 // C_i[g][j], g=0..7, j=0..7
  const int bid = blockIdx.x;
  const int t = threadIdx.x;
  if (bid < 1792) {
    const int r0 = bid << 2;               // global output row (n) base
    const int i = r0 >> 10;                // scale index 0..6 (uniform/block)
    const int scale = 8 - i;
    const int K = scale << 9;              // scale*512
    const int d0 = r0 - (i << 10);
    if (t < 64) {
      const int g = t >> 3, j = t & 7;
      float v = 0.f;
      if (j < scale) {
        const int* p = (i == 0) ? p0 : (i == 1) ? p1 : (i == 2) ? p2 :
                       (i == 3) ? p3 : (i == 4) ? p4 : (i == 5) ? p5 : p6;
        int cnt = 0;
        for (int s = 0; s < 12; ++s) cnt += (p[s * scale + j] == g) ? 1 : 0;
        v = (float)cnt * (1.0f / 12.0f);
      }
      sC[t] = v;
    }
    __syncthreads();
    const float* Wi = (i == 0) ? W0 : (i == 1) ? W1 : (i == 2) ? W2 :
                      (i == 3) ? W3 : (i == 4) ? W4 : (i == 5) ? W5 : W6;
    const int u = t & 63;                  // f-octet: f = u*8 .. u*8+7
    const int gq = t >> 6;                 // wave -> g pair {2gq, 2gq+1}
    u16* dst = Wtil + ((size_t)r0 << 12);  // r0 * 4096
    for (int r = 0; r < 4; ++r) {
      const float* wrow = Wi + (size_t)(d0 + r) * K;
      float a0[8], a1[8];
#pragma unroll
      for (int e = 0; e < 8; ++e) { a0[e] = 0.f; a1[e] = 0.f; }
      for (int j = 0; j < scale; ++j) {
        const float* wp = wrow + j * 512 + (u << 3);
        const float4 wa = *reinterpret_cast<const float4*>(wp);
        const float4 wb = *reinterpret_cast<const float4*>(wp + 4);
        const float c0 = sC[(gq << 4) + j];        // C[2gq][j]
        const float c1 = sC[(gq << 4) + 8 + j];    // C[2gq+1][j]
        a0[0] += c0 * wa.x; a0[1] += c0 * wa.y; a0[2] += c0 * wa.z; a0[3] += c0 * wa.w;
        a0[4] += c0 * wb.x; a0[5] += c0 * wb.y; a0[6] += c0 * wb.z; a0[7] += c0 * wb.w;
        a1[0] += c1 * wa.x; a1[1] += c1 * wa.y; a1[2] += c1 * wa.z; a1[3] += c1 * wa.w;
        a1[4] += c1 * wb.x; a1[5] += c1 * wb.y; a1[6] += c1 * wb.z; a1[7] += c1 * wb.w;
      }
      uint4 o0, o1;
      o0.x = (unsigned)f2bf(a0[0]) | ((unsigned)f2bf(a0[1]) << 16);
      o0.y = (unsigned)f2bf(a0[2]) | ((unsigned)f2bf(a0[3]) << 16);
      o0.z = (unsigned)f2bf(a0[4]) | ((unsigned)f2bf(a0[5]) << 16);
      o0.w = (unsigned)f2bf(a0[6]) | ((unsigned)f2bf(a0[7]) << 16);
      o1.x = (unsigned)f2bf(a1[0]) | ((unsigned)f2bf(a1[1]) << 16);
      o1.y = (unsigned)f2bf(a1[2]) | ((unsigned)f2bf(a1[3]) << 16);
      o1.z = (unsigned)f2bf(a1[4]) | ((unsigned)f2bf(a1[5]) << 16);
      o1.w = (unsigned)f2bf(a1[6]) | ((unsigned)f2bf(a1[7]) << 16);
      u16* drow = dst + ((size_t)r << 12) + (gq << 10) + (u << 3);
      *reinterpret_cast<uint4*>(drow) = o0;        // g = 2gq
      *reinterpret_cast<uint4*>(drow + 512) = o1;  // g = 2gq+1
    }
  } else {
    // x cast: 2048*4096 fp32 -> bf16
    const int tid0 = ((bid - 1792) << 8) | t;
    const float4* X4 = reinterpret_cast<const float4*>(x);
    uint4* O = reinterpret_cast<uint4*>(Xb16);
#pragma unroll 4
    for (int it = 0; it < 16; ++it) {
      const int e = tid0 + (it << 16);
      const float4 a = X4[(size_t)e * 2];
      const float4 c = X4[(size_t)e * 2 + 1];
      uint4 o;
      o.x = (unsigned)f2bf(a.x) | ((unsigned)f2bf(a.y) << 16);
      o.y = (unsigned)f2bf(a.z) | ((unsigned)f2bf(a.w) << 16);
      o.z = (unsigned)f2bf(c.x) | ((unsigned)f2bf(c.y) << 16);
      o.w = (unsigned)f2bf(c.z) | ((unsigned)f2bf(c.w) << 16);
      O[e] = o;
    }
  }
}

// ---------------------------------------------------------------------------
// Kernel 2: bf16 MFMA GEMM 2048 x 7168 x 4096, 256x256 tile, 8 waves,
// 32x32x16 MFMA, global-quadrant phases with READ-AHEAD.
//   LDS 128 KB: dbuf d at d*32768 u16; A-lo +0, A-hi +8192, B-lo +16384,
//   B-hi +24576.  Phases per K-tile t: Q1=(Mlo,Nlo) Q2=(Mlo,Nhi)
//   Q3=(Mhi,Nhi) Q4=(Mhi,Nlo); 8 waves split 128x128 as 2x4 -> 64x32/wave
//   = 2 m-frags x 4 kk x 32x32x16 = 8 MFMA/phase/wave.
//   Read-ahead: ph1:RD bHi(t)  ph2:RD aHi(t)  ph3:RD aLo(t+1)
//   ph4:[MFMA first] RD bLo(t+1)  ph5:RD bHi(t+1) ph6:RD aHi(t+1)
//   ph7:RD aLo(t+2) ph8:[MFMA first] RD bLo(t+2).
//   Stages (1 half-tile/phase; FIFO-verified: every stage's landing window
//   [issue-phase .. own-wave vmcnt retire + barrier] is disjoint from every
//   reader region): S1:Blo(2j+1) S2:Ahi(2j+1) S3:Alo(2j+2) S4:Bhi(2j+2)
//   S5:Blo(2j+2) S6:Ahi(2j+2) S7:Alo(2j+3) S8:Bhi(2j+3).
//   Waits: e1:vm6 e2:vm6 e3:vm4 e4:- e5:vm6 e6:vm6 e7:vm4 e8:-.
//   ONE barrier per phase. Rotation swizzle slot=(chunk+row)&7 (2-way max
//   per 16-lane service group = free; 0 measured conflicts on this pattern).
// ---------------------------------------------------------------------------
__device__ __forceinline__ void gl_lds16(const u16* g, u16* l) {
  __builtin_amdgcn_global_load_lds(
      (const __attribute__((address_space(1))) void*)g,
      (__attribute__((address_space(3))) void*)l, 16, 0, 0);
}

#define VM6 __builtin_amdgcn_s_waitcnt(0x0F76)
#define VM4 __builtin_amdgcn_s_waitcnt(0x0F74)
#define VM2 __builtin_amdgcn_s_waitcnt(0x0F72)
#define VM0 __builtin_amdgcn_s_waitcnt(0x0F70)
#define BAR __builtin_amdgcn_s_barrier()
#define PRIO1 __builtin_amdgcn_s_setprio(1)
#define PRIO0 __builtin_amdgcn_s_setprio(0)

// read A-half (2 m-frags x 4 kk) from lds base (db + 0 or db + 8192)
#define RD_A_(dst, BASE)                                                     \
  _Pragma("unroll")                                                          \
  for (int mf_ = 0; mf_ < 2; ++mf_)                                          \
    _Pragma("unroll")                                                        \
    for (int kk_ = 0; kk_ < 4; ++kk_)                                        \
      dst[mf_][kk_] = *reinterpret_cast<const bf16x8*>(lds + (BASE) + offA[mf_][kk_]);

// read B-half (4 kk) from lds base (db + 16384 or db + 24576)
#define RD_B_(dst, BASE)                                                     \
  _Pragma("unroll")                                                          \
  for (int kk_ = 0; kk_ < 4; ++kk_)                                          \
    dst[kk_] = *reinterpret_cast<const bf16x8*>(lds + (BASE) + offB[kk_]);

// 8 MFMA: acc[QD][mf] += A[mf][kk] * B[kk], 32x32x16
#define MFMA_Q(QD, AH, BH)                                                   \
  PRIO1;                                                                     \
  _Pragma("unroll")                                                          \
  for (int mf_ = 0; mf_ < 2; ++mf_)                                          \
    _Pragma("unroll")                                                        \
    for (int kk_ = 0; kk_ < 4; ++kk_)                                        \
      acc[QD][mf_] = __builtin_amdgcn_mfma_f32_32x32x16_bf16(                \
          AH[mf_][kk_], BH[kk_], acc[QD][mf_], 0, 0, 0);                     \
  PRIO0;

__global__ __launch_bounds__(512, 2) void k_gemm(
    const u16* __restrict__ A, const u16* __restrict__ Bm,
    const float* b0, const float* b1, const float* b2, const float* b3,
    const float* b4, const float* b5, const float* b6,
    float* __restrict__ out) {
  __shared__ u16 lds[65536];          // 128 KB
  const int bid = blockIdx.x;         // 224 = 8 m-tiles x 28 n-tiles
  const int blockM = (bid & 7) * 256;   // bid%8 = XCD: A-panel L2-resident
  const int blockN = (bid >> 3) * 256;

  const int tid = threadIdx.x;        // 512 threads, 8 waves
  const int lane = tid & 63;
  const int wid = tid >> 6;
  const int wm = (wid >> 2) * 64;     // row offset within 128-row quadrant
  const int wn = (wid & 3) * 32;      // col offset within 128-col quadrant
  const int l31 = lane & 31;
  const int hi = lane >> 5;           // k-octet select for 32x32x16 A/B frags

  // ---- staging addresses (2 chunks per half-tile per thread) ----
  const int srow = tid >> 3;          // 0..63
  const int sslot = tid & 7;
  const int gch = (sslot - srow) & 7; // rotation swizzle (source side)
  const u16* gA0 = A + (size_t)(blockM + srow) * 4096 + gch * 8;
  const u16* gB0 = Bm + (size_t)(blockN + srow) * 4096 + gch * 8;

  // ---- LDS read offsets (u16 units within a half; chunk c=2*kk+hi) ----
  int offA[2][4], offB[4];
#pragma unroll
  for (int mf = 0; mf < 2; ++mf)
#pragma unroll
    for (int kk = 0; kk < 4; ++kk) {
      const int r = wm + mf * 32 + l31;            // 0..127
      offA[mf][kk] = r * 64 + (((2 * kk + hi) + r) & 7) * 8;
    }
#pragma unroll
  for (int kk = 0; kk < 4; ++kk) {
    const int r = wn + l31;                        // 0..127
    offB[kk] = r * 64 + (((2 * kk + hi) + r) & 7) * 8;
  }

  f32x16 acc[4][2];
#pragma unroll
  for (int q = 0; q < 4; ++q)
#pragma unroll
    for (int m = 0; m < 2; ++m)
#pragma unroll
      for (int e = 0; e < 16; ++e) acc[q][m][e] = 0.f;

  // stage one half-tile: mat 0=A 1=B, half h, K-tile t, dbuf base db (u16)
  auto stage = [&](int mat, int h, int t, int db) {
    const u16* g = (mat ? gB0 : gA0) + (size_t)h * (128 * 4096) + (size_t)t * 64;
    u16* l = lds + db + mat * 16384 + h * 8192 + (tid << 3);
    gl_lds16(g, l);
    gl_lds16(g + (size_t)(64 * 4096), l + 4096);
  };

  bf16x8 aLo[2][4], aHi[2][4], bLo[4], bHi[4];

  // ---- prologue: t0 full -> db0; t1 {Alo,Bhi} -> db1 (j=0 stages the rest).
  // PROTOCOL: vmcnt(0) retires OWN-wave loads; the barrier is what makes ALL
  // waves' staged rows visible. Reads must come AFTER the barrier (round-5
  // bug: reads were before it).
  stage(0, 0, 0, 0); stage(1, 0, 0, 0); stage(1, 1, 0, 0); stage(0, 1, 0, 0);
  stage(0, 0, 1, 32768); stage(1, 1, 1, 32768);
  VM0;
  BAR;
  RD_A_(aLo, 0)             // aLo(t0)
  RD_B_(bLo, 16384)         // bLo(t0)

  for (int j = 0; j < 31; ++j) {      // tiles t=2j, t+1; stages through 2j+3
    const int t1 = 2 * j + 1;
    const int t2 = 2 * j + 2;
    const int t3 = 2 * j + 3;

    // ph1: Q1(t); RD bHi(t); S1=Blo(t1)->db1
    RD_B_(bHi, 24576)
    stage(1, 0, t1, 32768);
    MFMA_Q(0, aLo, bLo)
    VM6; BAR;

    // ph2: Q2(t); RD aHi(t); S2=Ahi(t1)->db1
    RD_A_(aHi, 8192)
    stage(0, 1, t1, 32768);
    MFMA_Q(1, aLo, bHi)
    VM6; BAR;

    // ph3: Q3(t); RD aLo(t+1); S3=Alo(t2)->db0
    RD_A_(aLo, 32768)
    stage(0, 0, t2, 0);
    MFMA_Q(2, aHi, bHi)
    VM4; BAR;

    // ph4: Q4(t); S4=Bhi(t2)->db0; late RD bLo(t+1)
    stage(1, 1, t2, 0);
    MFMA_Q(3, aHi, bLo)
    RD_B_(bLo, 32768 + 16384)
    BAR;

    // ph5: Q1(t+1); RD bHi(t+1); S5=Blo(t2)->db0
    RD_B_(bHi, 32768 + 24576)
    stage(1, 0, t2, 0);
    MFMA_Q(0, aLo, bLo)
    VM6; BAR;

    // ph6: Q2(t+1); RD aHi(t+1); S6=Ahi(t2)->db0
    RD_A_(aHi, 32768 + 8192)
    stage(0, 1, t2, 0);
    MFMA_Q(1, aLo, bHi)
    VM6; BAR;

    // ph7: Q3(t+1); RD aLo(t+2); S7=Alo(t3)->db1
    RD_A_(aLo, 0)
    stage(0, 0, t3, 32768);
    MFMA_Q(2, aHi, bHi)
    VM4; BAR;

    // ph8: Q4(t+1); S8=Bhi(t3)->db1; late RD bLo(t+2)
    stage(1, 1, t3, 32768);
    MFMA_Q(3, aHi, bLo)
    RD_B_(bLo, 16384)
    BAR;
  }

  // ---- drain: tiles 62 (db0) / 63 (db1); only stages Blo(63), Ahi(63). ----
  {
    // dph1: Q1(62); RD bHi(62); stage Blo(63)->db1
    RD_B_(bHi, 24576)
    stage(1, 0, 63, 32768);
    MFMA_Q(0, aLo, bLo)
    VM6; BAR;

    // dph2: Q2(62); RD aHi(62); stage Ahi(63)->db1
    RD_A_(aHi, 8192)
    stage(0, 1, 63, 32768);
    MFMA_Q(1, aLo, bHi)
    VM6; BAR;

    // dph3: Q3(62); RD aLo(63)
    RD_A_(aLo, 32768)
    MFMA_Q(2, aHi, bHi)
    VM2; BAR;

    // dph4: Q4(62); late RD bLo(63)
    MFMA_Q(3, aHi, bLo)
    RD_B_(bLo, 32768 + 16384)
    BAR;

    // dph5: Q1(63); RD bHi(63)
    RD_B_(bHi, 32768 + 24576)
    MFMA_Q(0, aLo, bLo)
    VM0; BAR;

    // dph6: Q2(63); RD aHi(63)
    RD_A_(aHi, 32768 + 8192)
    MFMA_Q(1, aLo, bHi)
    BAR;

    // dph7: Q3(63)
    MFMA_Q(2, aHi, bHi)
    BAR;

    // dph8: Q4(63)
    MFMA_Q(3, aHi, bLo)
  }

  // ---- epilogue: 32x32 C/D: col = lane&31, row = (reg&3)+8*(reg>>2)+4*hi ----
  const int isc = blockN >> 10;
  const float* bi = (isc == 0) ? b0 : (isc == 1) ? b1 : (isc == 2) ? b2 :
                    (isc == 3) ? b3 : (isc == 4) ? b4 : (isc == 5) ? b5 : b6;
#pragma unroll
  for (int qd = 0; qd < 4; ++qd) {
    const int Mq = (qd >= 2) ? 128 : 0;
    const int Nq = (qd == 1 || qd == 2) ? 128 : 0;
    const int col = blockN + Nq + wn + l31;
    const float bias = bi[col & 1023];
#pragma unroll
    for (int mf = 0; mf < 2; ++mf) {
      const int rbase = blockM + Mq + wm + mf * 32 + 4 * hi;
#pragma unroll
      for (int reg = 0; reg < 16; ++reg) {
        const int row = rbase + (reg & 3) + 8 * (reg >> 2);
        out[(size_t)row * 7168 + col] = acc[qd][mf][reg] + bias;
      }
    }
  }
}

// ---------------------------------------------------------------------------
extern "C" void kernel_launch(void* const* d_in, const int* in_sizes, int n_in,
                              void* d_out, int out_size, void* d_ws, size_t ws_size,
                              hipStream_t stream) {
  const float* input = (const float*)d_in[0];
  const int* perms[7];
  const float* W[7];
  const float* bias[7];
  for (int i = 0; i < 7; ++i) {
    perms[i] = (const int*)d_in[1 + 3 * i];
    W[i]     = (const float*)d_in[2 + 3 * i];
    bias[i]  = (const float*)d_in[3 + 3 * i];
  }
  char* ws = (char*)d_ws;
  u16* Xb16 = (u16*)ws;                                // 2048*4096 bf16 = 16.8 MB
  u16* Wtil = (u16*)(ws + (size_t)2048 * 4096 * 2);    // 7168*4096 bf16 = 58.7 MB

  k_prep<<<2048, 256, 0, stream>>>(input,
                                   perms[0], perms[1], perms[2], perms[3],
                                   perms[4], perms[5], perms[6],
                                   W[0], W[1], W[2], W[3], W[4], W[5], W[6],
                                   Xb16, Wtil);
  k_gemm<<<224, 512, 0, stream>>>(Xb16, Wtil,
                                  bias[0], bias[1], bias[2], bias[3],
                                  bias[4], bias[5], bias[6],
                                  (float*)d_out);
}